// Round 1
// baseline (500.933 us; speedup 1.0000x reference)
//
#include <hip/hip_runtime.h>

#define N_NODES 100000
#define N_EDGES 1600000
#define MPAD    100096   /* 782 * 128 */
#define MTILES  782

typedef __attribute__((ext_vector_type(8))) short short8;
typedef __attribute__((ext_vector_type(4))) float f32x4;

static __device__ __forceinline__ unsigned short f2bf(float f) {
  unsigned u = __builtin_bit_cast(unsigned, f);
  u += 0x7fffu + ((u >> 16) & 1u);     // round-to-nearest-even
  return (unsigned short)(u >> 16);
}
static __device__ __forceinline__ float bf2f(unsigned short s) {
  unsigned u = ((unsigned)s) << 16;
  return __builtin_bit_cast(float, u);
}

__global__ void k_zero(int* __restrict__ p, int n) {
  int i = blockIdx.x * 256 + threadIdx.x;
  if (i < n) p[i] = 0;
}

__global__ void k_hist(const int* __restrict__ row, int* __restrict__ deg) {
  int i = blockIdx.x * 256 + threadIdx.x;
  if (i < N_EDGES) atomicAdd(&deg[row[i]], 1);
}

// ---- 3-kernel exclusive scan of deg[N] -> rp[N+1], chunk = 2048/block ----
__global__ void k_scan1(const int* __restrict__ deg, int* __restrict__ bsum) {
  int b = blockIdx.x, t = threadIdx.x;
  int base = b * 2048 + t * 8;
  int s = 0;
  #pragma unroll
  for (int j = 0; j < 8; ++j) {
    int idx = base + j;
    s += (idx < N_NODES) ? deg[idx] : 0;
  }
  #pragma unroll
  for (int off = 32; off > 0; off >>= 1) s += __shfl_down(s, off, 64);
  __shared__ int ws[4];
  if ((t & 63) == 0) ws[t >> 6] = s;
  __syncthreads();
  if (t == 0) bsum[b] = ws[0] + ws[1] + ws[2] + ws[3];
}

__global__ void k_scan2(const int* __restrict__ bsum, int* __restrict__ boff,
                        int* __restrict__ rp, int nblk) {
  int l = threadIdx.x;  // 64 threads, nblk <= 64
  int v = (l < nblk) ? bsum[l] : 0;
  int incl = v;
  #pragma unroll
  for (int off = 1; off < 64; off <<= 1) {
    int n = __shfl_up(incl, off, 64);
    if (l >= off) incl += n;
  }
  if (l < nblk) boff[l] = incl - v;
  if (l == 63) rp[N_NODES] = incl;   // total = E
}

__global__ void k_scan3(const int* __restrict__ deg, const int* __restrict__ boff,
                        int* __restrict__ rp) {
  int b = blockIdx.x, t = threadIdx.x;
  int base = b * 2048 + t * 8;
  int v[8]; int s = 0;
  #pragma unroll
  for (int j = 0; j < 8; ++j) {
    int idx = base + j;
    v[j] = (idx < N_NODES) ? deg[idx] : 0;
    s += v[j];
  }
  int lane = t & 63, w = t >> 6;
  int incl = s;
  #pragma unroll
  for (int off = 1; off < 64; off <<= 1) {
    int n = __shfl_up(incl, off, 64);
    if (lane >= off) incl += n;
  }
  __shared__ int ws[4];
  if (lane == 63) ws[w] = incl;
  __syncthreads();
  int wo = 0;
  for (int ww = 0; ww < w; ++ww) wo += ws[ww];
  int run = boff[b] + wo + (incl - s);
  #pragma unroll
  for (int j = 0; j < 8; ++j) {
    int idx = base + j;
    if (idx < N_NODES) rp[idx] = run;
    run += v[j];
  }
}

__global__ void k_initcur(const int* __restrict__ rp, int* __restrict__ cur) {
  int i = blockIdx.x * 256 + threadIdx.x;
  if (i < N_NODES) cur[i] = rp[i];
}

__global__ void k_fill(const int* __restrict__ row, const int* __restrict__ col,
                       int* __restrict__ cur, int* __restrict__ cs) {
  int i = blockIdx.x * 256 + threadIdx.x;
  if (i < N_EDGES) {
    int r = row[i];
    int p = atomicAdd(&cur[r], 1);
    cs[p] = col[i];
  }
}

// x f32 -> bf16 into Acat[:,128:256]
__global__ void k_cvt_x(const float* __restrict__ x, short* __restrict__ Acat) {
  int id = blockIdx.x * 256 + threadIdx.x;
  if (id >= N_NODES * 32) return;
  int node = id >> 5, c4 = id & 31;
  float4 v = *(const float4*)(x + (size_t)node * 128 + c4 * 4);
  uint2 u;
  u.x = (unsigned)f2bf(v.x) | ((unsigned)f2bf(v.y) << 16);
  u.y = (unsigned)f2bf(v.z) | ((unsigned)f2bf(v.w) << 16);
  *(uint2*)(Acat + (size_t)node * 256 + 128 + c4 * 4) = u;
}

// agg over bf16 x (read Acat[:,128:256]) -> bf16 into Acat[:,0:128]. 1 wave/node.
__global__ __launch_bounds__(256) void k_agg_x(const int* __restrict__ rp,
                                               const int* __restrict__ cs,
                                               short* __restrict__ Acat) {
  int node = blockIdx.x * 4 + (threadIdx.x >> 6);
  if (node >= N_NODES) return;
  int lane = threadIdx.x & 63;
  int s = rp[node], e = rp[node + 1];
  float a0 = 0.f, a1 = 0.f;
  const short* xb = Acat + 128 + 2 * lane;
  int i = s;
  for (; i + 4 <= e; i += 4) {
    int j0 = cs[i], j1 = cs[i + 1], j2 = cs[i + 2], j3 = cs[i + 3];
    unsigned u0 = *(const unsigned*)(xb + (size_t)j0 * 256);
    unsigned u1 = *(const unsigned*)(xb + (size_t)j1 * 256);
    unsigned u2 = *(const unsigned*)(xb + (size_t)j2 * 256);
    unsigned u3 = *(const unsigned*)(xb + (size_t)j3 * 256);
    a0 += (bf2f((unsigned short)u0) + bf2f((unsigned short)u1))
        + (bf2f((unsigned short)u2) + bf2f((unsigned short)u3));
    a1 += (bf2f((unsigned short)(u0 >> 16)) + bf2f((unsigned short)(u1 >> 16)))
        + (bf2f((unsigned short)(u2 >> 16)) + bf2f((unsigned short)(u3 >> 16)));
  }
  for (; i < e; ++i) {
    unsigned u = *(const unsigned*)(xb + (size_t)cs[i] * 256);
    a0 += bf2f((unsigned short)u);
    a1 += bf2f((unsigned short)(u >> 16));
  }
  *(unsigned*)(Acat + (size_t)node * 256 + 2 * lane) =
      (unsigned)f2bf(a0) | ((unsigned)f2bf(a1) << 16);
}

// agg over bf16 h (read Hcat[:,256:512]) -> bf16 into Hcat[:,0:256]. 1 wave/node.
__global__ __launch_bounds__(256) void k_agg_h(const int* __restrict__ rp,
                                               const int* __restrict__ cs,
                                               short* __restrict__ Hcat) {
  int node = blockIdx.x * 4 + (threadIdx.x >> 6);
  if (node >= N_NODES) return;
  int lane = threadIdx.x & 63;
  int s = rp[node], e = rp[node + 1];
  float a0 = 0.f, a1 = 0.f, a2 = 0.f, a3 = 0.f;
  const short* hb = Hcat + 256 + 4 * lane;
  int i = s;
  for (; i + 2 <= e; i += 2) {
    int j0 = cs[i], j1 = cs[i + 1];
    uint2 u0 = *(const uint2*)(hb + (size_t)j0 * 512);
    uint2 u1 = *(const uint2*)(hb + (size_t)j1 * 512);
    a0 += bf2f((unsigned short)u0.x) + bf2f((unsigned short)u1.x);
    a1 += bf2f((unsigned short)(u0.x >> 16)) + bf2f((unsigned short)(u1.x >> 16));
    a2 += bf2f((unsigned short)u0.y) + bf2f((unsigned short)u1.y);
    a3 += bf2f((unsigned short)(u0.y >> 16)) + bf2f((unsigned short)(u1.y >> 16));
  }
  for (; i < e; ++i) {
    uint2 u = *(const uint2*)(hb + (size_t)cs[i] * 512);
    a0 += bf2f((unsigned short)u.x);
    a1 += bf2f((unsigned short)(u.x >> 16));
    a2 += bf2f((unsigned short)u.y);
    a3 += bf2f((unsigned short)(u.y >> 16));
  }
  uint2 o;
  o.x = (unsigned)f2bf(a0) | ((unsigned)f2bf(a1) << 16);
  o.y = (unsigned)f2bf(a2) | ((unsigned)f2bf(a3) << 16);
  *(uint2*)(Hcat + (size_t)node * 512 + 4 * lane) = o;
}

// pack B = vstack(B0, B1) [K x GN] f32 -> bf16 MFMA-B fragment layout
// Bp[((kk*NB + nb)*64 + lane)*8 + j] = B[kk*32 + (lane>>4)*8 + j][nb*16 + (lane&15)]
__global__ void k_pack(const float* __restrict__ B0, const float* __restrict__ B1,
                       short* __restrict__ Bp, int K, int GN) {
  int id = blockIdx.x * 256 + threadIdx.x;
  if (id >= K * GN) return;
  int j = id & 7;
  int lane = (id >> 3) & 63;
  int blk = id >> 9;
  int NB = GN >> 4;
  int nb = blk % NB;
  int kk = blk / NB;
  int k = kk * 32 + (lane >> 4) * 8 + j;
  int c = nb * 16 + (lane & 15);
  int halfK = K >> 1;
  float v = (k < halfK) ? B0[k * GN + c] : B1[(k - halfK) * GN + c];
  Bp[id] = (short)f2bf(v);
}

// C[M x GN] = A[M x K](bf16) * Bp + bias, optional relu.
// 128x128 tile / block, 4 waves 2x2, each wave 64x64 (4x4 16x16x32 frags).
// A frags and packed-B frags loaded straight from global (B is L2-resident).
template <int KK, int NBTOT, bool RELU, bool OUT_BF16>
__global__ __launch_bounds__(256) void k_gemm(const short* __restrict__ A, int lda,
                                              const short* __restrict__ Bp,
                                              const float* __restrict__ bias,
                                              void* __restrict__ out, int ldc,
                                              int col_off, int mlimit) {
  const int lane = threadIdx.x & 63;
  const int wave = threadIdx.x >> 6;
  const int wr = wave >> 1, wc = wave & 1;
  const int row0 = blockIdx.x * 128 + wr * 64;
  const int colbase = blockIdx.y * 128 + wc * 64;
  const int arow = lane & 15;
  const int kgrp = lane >> 4;

  f32x4 acc[4][4];
  const f32x4 zero = {0.f, 0.f, 0.f, 0.f};
  #pragma unroll
  for (int a = 0; a < 4; ++a)
    #pragma unroll
    for (int b = 0; b < 4; ++b) acc[a][b] = zero;

  const short* Bbase = Bp + (size_t)lane * 8;
  for (int kk = 0; kk < KK; ++kk) {
    short8 af[4], bfr[4];
    const int kb = kk * 32 + kgrp * 8;
    #pragma unroll
    for (int mi = 0; mi < 4; ++mi)
      af[mi] = *(const short8*)(A + (size_t)(row0 + mi * 16 + arow) * lda + kb);
    #pragma unroll
    for (int ni = 0; ni < 4; ++ni) {
      int nb = (colbase >> 4) + ni;
      bfr[ni] = *(const short8*)(Bbase + ((size_t)(kk * NBTOT + nb) << 9));
    }
    #pragma unroll
    for (int mi = 0; mi < 4; ++mi)
      #pragma unroll
      for (int ni = 0; ni < 4; ++ni)
        acc[mi][ni] = __builtin_amdgcn_mfma_f32_16x16x32_bf16(af[mi], bfr[ni],
                                                              acc[mi][ni], 0, 0, 0);
  }

  const int ccol = lane & 15;
  const int crow = (lane >> 4) * 4;
  #pragma unroll
  for (int ni = 0; ni < 4; ++ni) {
    const int colg = colbase + ni * 16 + ccol;
    const float bv = bias[colg];
    #pragma unroll
    for (int mi = 0; mi < 4; ++mi) {
      #pragma unroll
      for (int j = 0; j < 4; ++j) {
        int rowg = row0 + mi * 16 + crow + j;
        float v = acc[mi][ni][j] + bv;
        if (RELU) v = fmaxf(v, 0.0f);
        if (OUT_BF16) {
          ((short*)out)[(size_t)rowg * ldc + col_off + colg] = (short)f2bf(v);
        } else {
          if (rowg < mlimit)
            ((float*)out)[(size_t)rowg * ldc + col_off + colg] = v;
        }
      }
    }
  }
}

extern "C" void kernel_launch(void* const* d_in, const int* in_sizes, int n_in,
                              void* d_out, int out_size, void* d_ws, size_t ws_size,
                              hipStream_t stream) {
  const float* x   = (const float*)d_in[0];
  const int*   row = (const int*)d_in[1];
  const int*   col = (const int*)d_in[2];
  const float* Wl1 = (const float*)d_in[3];
  const float* bl1 = (const float*)d_in[4];
  const float* Wr1 = (const float*)d_in[5];
  const float* Wl2 = (const float*)d_in[6];
  const float* bl2 = (const float*)d_in[7];
  const float* Wr2 = (const float*)d_in[8];
  float* out = (float*)d_out;

  char* w = (char*)d_ws;
  auto alloc = [&](size_t bytes) {
    char* p = w;
    w += (bytes + 255) & ~(size_t)255;
    return p;
  };
  short* Acat = (short*)alloc((size_t)MPAD * 256 * 2);  // [agg_x_bf16 | x_bf16]
  short* Hcat = (short*)alloc((size_t)MPAD * 512 * 2);  // [agg_h_bf16 | h_bf16]
  short* Bp1  = (short*)alloc(65536 * 2);               // [Wl1;Wr1] packed
  short* Bp2  = (short*)alloc(65536 * 2);               // [Wl2;Wr2] packed
  int* rp   = (int*)alloc((N_NODES + 1) * 4);
  int* deg  = (int*)alloc(N_NODES * 4);
  int* cur  = (int*)alloc(N_NODES * 4);
  int* cs   = (int*)alloc((size_t)N_EDGES * 4);
  int* bsum = (int*)alloc(64 * 4);
  int* boff = (int*)alloc(64 * 4);

  const int NBLK = (N_NODES + 2047) / 2048;  // 49

  // --- CSR build ---
  k_zero<<<(N_NODES + 255) / 256, 256, 0, stream>>>(deg, N_NODES);
  k_hist<<<(N_EDGES + 255) / 256, 256, 0, stream>>>(row, deg);
  k_scan1<<<NBLK, 256, 0, stream>>>(deg, bsum);
  k_scan2<<<1, 64, 0, stream>>>(bsum, boff, rp, NBLK);
  k_scan3<<<NBLK, 256, 0, stream>>>(deg, boff, rp);
  k_initcur<<<(N_NODES + 255) / 256, 256, 0, stream>>>(rp, cur);
  k_fill<<<(N_EDGES + 255) / 256, 256, 0, stream>>>(row, col, cur, cs);

  // --- weight packing + x conversion (independent of CSR) ---
  k_cvt_x<<<(N_NODES * 32 + 255) / 256, 256, 0, stream>>>(x, Acat);
  k_pack<<<256, 256, 0, stream>>>(Wl1, Wr1, Bp1, 256, 256);
  k_pack<<<256, 256, 0, stream>>>(Wl2, Wr2, Bp2, 512, 128);

  // --- layer 1: agg(x) ; h = relu([agg|x] @ [Wl1;Wr1] + bl1) ---
  k_agg_x<<<(N_NODES + 3) / 4, 256, 0, stream>>>(rp, cs, Acat);
  k_gemm<8, 16, true, true><<<dim3(MTILES, 2), 256, 0, stream>>>(
      Acat, 256, Bp1, bl1, Hcat, 512, 256, MPAD);

  // --- layer 2: agg(h) ; out = [agg|h] @ [Wl2;Wr2] + bl2 ---
  k_agg_h<<<(N_NODES + 3) / 4, 256, 0, stream>>>(rp, cs, Hcat);
  k_gemm<16, 8, false, false><<<dim3(MTILES, 1), 256, 0, stream>>>(
      Hcat, 512, Bp2, bl2, out, 128, 0, N_NODES);
}

// Round 2
// 353.474 us; speedup vs baseline: 1.4172x; 1.4172x over previous
//
#include <hip/hip_runtime.h>

#define N_NODES 100000
#define N_EDGES 1600000
#define MPAD    100096   /* 782 * 128 */
#define MTILES  782

#define NB      391      /* ceil(100000/256) buckets of 256 nodes */
#define CH      8192     /* edges per phase-A block */
#define NBLK_A  196      /* ceil(1600000/8192) */

typedef __attribute__((ext_vector_type(8))) short short8;
typedef __attribute__((ext_vector_type(4))) float f32x4;

static __device__ __forceinline__ unsigned short f2bf(float f) {
  unsigned u = __builtin_bit_cast(unsigned, f);
  u += 0x7fffu + ((u >> 16) & 1u);     // round-to-nearest-even
  return (unsigned short)(u >> 16);
}
static __device__ __forceinline__ float bf2f(unsigned short s) {
  unsigned u = ((unsigned)s) << 16;
  return __builtin_bit_cast(float, u);
}

// ---------------- CSR build: two-level LDS counting sort ----------------

// Per-(block,bucket) histogram. Hc[bucket][block].
__global__ __launch_bounds__(256) void k_bhist(const int* __restrict__ row,
                                               int* __restrict__ Hc) {
  __shared__ int hist[NB];
  int b = blockIdx.x, t = threadIdx.x;
  for (int j = t; j < NB; j += 256) hist[j] = 0;
  __syncthreads();
  int base = b * CH;
  #pragma unroll
  for (int k = 0; k < 8; ++k) {
    int i = base + k * 1024 + t * 4;
    if (i < N_EDGES) {
      int4 r = *(const int4*)(row + i);
      atomicAdd(&hist[r.x >> 8], 1);
      atomicAdd(&hist[r.y >> 8], 1);
      atomicAdd(&hist[r.z >> 8], 1);
      atomicAdd(&hist[r.w >> 8], 1);
    }
  }
  __syncthreads();
  for (int j = t; j < NB; j += 256) Hc[j * NBLK_A + b] = hist[j];
}

// Exclusive scan of bucket totals -> Boff[NB+1]. One block.
__global__ __launch_bounds__(512) void k_bscan(const int* __restrict__ Hc,
                                               int* __restrict__ Boff) {
  int t = threadIdx.x;
  int total = 0;
  if (t < NB) {
    const int* p = Hc + t * NBLK_A;
    for (int i = 0; i < NBLK_A; i += 4) {
      int4 v = *(const int4*)(p + i);
      total += v.x + v.y + v.z + v.w;
    }
  }
  int lane = t & 63, w = t >> 6;
  int incl = total;
  #pragma unroll
  for (int off = 1; off < 64; off <<= 1) {
    int n = __shfl_up(incl, off, 64);
    if (lane >= off) incl += n;
  }
  __shared__ int ws[8];
  if (lane == 63) ws[w] = incl;
  __syncthreads();
  int wo = 0;
  for (int ww = 0; ww < w; ++ww) wo += ws[ww];
  int excl = wo + incl - total;
  if (t < NB) Boff[t] = excl;
  if (t == NB - 1) Boff[NB] = excl + total;
}

// Per-bucket scan across blocks -> G[bucket][block] global write bases.
__global__ __launch_bounds__(64) void k_bexp(const int* __restrict__ Hc,
                                             const int* __restrict__ Boff,
                                             int* __restrict__ G) {
  int b = blockIdx.x, l = threadIdx.x;
  int run = Boff[b];
  const int* p = Hc + b * NBLK_A;
  for (int c = 0; c < NBLK_A; c += 64) {
    int idx = c + l;
    int v = (idx < NBLK_A) ? p[idx] : 0;
    int incl = v;
    #pragma unroll
    for (int off = 1; off < 64; off <<= 1) {
      int n = __shfl_up(incl, off, 64);
      if (l >= off) incl += n;
    }
    if (idx < NBLK_A) G[b * NBLK_A + idx] = run + incl - v;
    run += __shfl(incl, 63, 64);
  }
}

// Scatter edges into bucket regions, packed: col | (row&255)<<24.
__global__ __launch_bounds__(256) void k_bscat(const int* __restrict__ row,
                                               const int* __restrict__ col,
                                               const int* __restrict__ G,
                                               unsigned* __restrict__ tmp) {
  __shared__ int cur[NB];
  int b = blockIdx.x, t = threadIdx.x;
  for (int j = t; j < NB; j += 256) cur[j] = G[j * NBLK_A + b];
  __syncthreads();
  int base = b * CH;
  #pragma unroll
  for (int k = 0; k < 8; ++k) {
    int i = base + k * 1024 + t * 4;
    if (i < N_EDGES) {
      int4 r = *(const int4*)(row + i);
      int4 c = *(const int4*)(col + i);
      int p0 = atomicAdd(&cur[r.x >> 8], 1);
      tmp[p0] = (unsigned)c.x | ((unsigned)(r.x & 255) << 24);
      int p1 = atomicAdd(&cur[r.y >> 8], 1);
      tmp[p1] = (unsigned)c.y | ((unsigned)(r.y & 255) << 24);
      int p2 = atomicAdd(&cur[r.z >> 8], 1);
      tmp[p2] = (unsigned)c.z | ((unsigned)(r.z & 255) << 24);
      int p3 = atomicAdd(&cur[r.w >> 8], 1);
      tmp[p3] = (unsigned)c.w | ((unsigned)(r.w & 255) << 24);
    }
  }
}

// Within-bucket counting sort: writes rp and cs. One block per bucket.
__global__ __launch_bounds__(256) void k_bsort(const unsigned* __restrict__ tmp,
                                               const int* __restrict__ Boff,
                                               int* __restrict__ rp,
                                               int* __restrict__ cs) {
  __shared__ int hist[256];
  __shared__ int wsum[4];
  int b = blockIdx.x, t = threadIdx.x;
  int s = Boff[b], e = Boff[b + 1];
  hist[t] = 0;
  __syncthreads();
  for (int i = s + t; i < e; i += 256) atomicAdd(&hist[tmp[i] >> 24], 1);
  __syncthreads();
  int v = hist[t];
  int lane = t & 63, w = t >> 6;
  int incl = v;
  #pragma unroll
  for (int off = 1; off < 64; off <<= 1) {
    int n = __shfl_up(incl, off, 64);
    if (lane >= off) incl += n;
  }
  if (lane == 63) wsum[w] = incl;
  __syncthreads();
  int wo = 0;
  for (int ww = 0; ww < w; ++ww) wo += wsum[ww];
  int excl = s + wo + incl - v;
  int node = (b << 8) + t;
  if (node < N_NODES) rp[node] = excl;
  __syncthreads();
  hist[t] = excl;    // reuse as cursor
  __syncthreads();
  for (int i = s + t; i < e; i += 256) {
    unsigned u = tmp[i];
    int pos = atomicAdd(&hist[u >> 24], 1);
    cs[pos] = (int)(u & 0xFFFFFFu);
  }
  if (b == 0 && t == 0) rp[N_NODES] = N_EDGES;
}

// ---------------- feature conversion / aggregation ----------------

// x f32 -> bf16 into Acat[:,128:256]
__global__ void k_cvt_x(const float* __restrict__ x, short* __restrict__ Acat) {
  int id = blockIdx.x * 256 + threadIdx.x;
  if (id >= N_NODES * 32) return;
  int node = id >> 5, c4 = id & 31;
  float4 v = *(const float4*)(x + (size_t)node * 128 + c4 * 4);
  uint2 u;
  u.x = (unsigned)f2bf(v.x) | ((unsigned)f2bf(v.y) << 16);
  u.y = (unsigned)f2bf(v.z) | ((unsigned)f2bf(v.w) << 16);
  *(uint2*)(Acat + (size_t)node * 256 + 128 + c4 * 4) = u;
}

// agg over bf16 x (read Acat[:,128:256]) -> bf16 into Acat[:,0:128]. 1 wave/node.
__global__ __launch_bounds__(256) void k_agg_x(const int* __restrict__ rp,
                                               const int* __restrict__ cs,
                                               short* __restrict__ Acat) {
  int node = blockIdx.x * 4 + (threadIdx.x >> 6);
  if (node >= N_NODES) return;
  int lane = threadIdx.x & 63;
  int s = rp[node], e = rp[node + 1];
  float a0 = 0.f, a1 = 0.f;
  const short* xb = Acat + 128 + 2 * lane;
  int i = s;
  for (; i + 8 <= e; i += 8) {
    unsigned u[8];
    #pragma unroll
    for (int q = 0; q < 8; ++q)
      u[q] = *(const unsigned*)(xb + (size_t)cs[i + q] * 256);
    #pragma unroll
    for (int q = 0; q < 8; ++q) {
      a0 += bf2f((unsigned short)u[q]);
      a1 += bf2f((unsigned short)(u[q] >> 16));
    }
  }
  for (; i < e; ++i) {
    unsigned u = *(const unsigned*)(xb + (size_t)cs[i] * 256);
    a0 += bf2f((unsigned short)u);
    a1 += bf2f((unsigned short)(u >> 16));
  }
  *(unsigned*)(Acat + (size_t)node * 256 + 2 * lane) =
      (unsigned)f2bf(a0) | ((unsigned)f2bf(a1) << 16);
}

// agg over bf16 h (read Hcat[:,256:512]) -> bf16 into Hcat[:,0:256]. 1 wave/node.
__global__ __launch_bounds__(256) void k_agg_h(const int* __restrict__ rp,
                                               const int* __restrict__ cs,
                                               short* __restrict__ Hcat) {
  int node = blockIdx.x * 4 + (threadIdx.x >> 6);
  if (node >= N_NODES) return;
  int lane = threadIdx.x & 63;
  int s = rp[node], e = rp[node + 1];
  float a0 = 0.f, a1 = 0.f, a2 = 0.f, a3 = 0.f;
  const short* hb = Hcat + 256 + 4 * lane;
  int i = s;
  for (; i + 4 <= e; i += 4) {
    uint2 u[4];
    #pragma unroll
    for (int q = 0; q < 4; ++q)
      u[q] = *(const uint2*)(hb + (size_t)cs[i + q] * 512);
    #pragma unroll
    for (int q = 0; q < 4; ++q) {
      a0 += bf2f((unsigned short)u[q].x);
      a1 += bf2f((unsigned short)(u[q].x >> 16));
      a2 += bf2f((unsigned short)u[q].y);
      a3 += bf2f((unsigned short)(u[q].y >> 16));
    }
  }
  for (; i < e; ++i) {
    uint2 u = *(const uint2*)(hb + (size_t)cs[i] * 512);
    a0 += bf2f((unsigned short)u.x);
    a1 += bf2f((unsigned short)(u.x >> 16));
    a2 += bf2f((unsigned short)u.y);
    a3 += bf2f((unsigned short)(u.y >> 16));
  }
  uint2 o;
  o.x = (unsigned)f2bf(a0) | ((unsigned)f2bf(a1) << 16);
  o.y = (unsigned)f2bf(a2) | ((unsigned)f2bf(a3) << 16);
  *(uint2*)(Hcat + (size_t)node * 512 + 4 * lane) = o;
}

// ---------------- GEMM ----------------

// pack B = vstack(B0, B1) [K x GN] f32 -> bf16 MFMA-B fragment layout
__global__ void k_pack(const float* __restrict__ B0, const float* __restrict__ B1,
                       short* __restrict__ Bp, int K, int GN) {
  int id = blockIdx.x * 256 + threadIdx.x;
  if (id >= K * GN) return;
  int j = id & 7;
  int lane = (id >> 3) & 63;
  int blk = id >> 9;
  int NBf = GN >> 4;
  int nb = blk % NBf;
  int kk = blk / NBf;
  int k = kk * 32 + (lane >> 4) * 8 + j;
  int c = nb * 16 + (lane & 15);
  int halfK = K >> 1;
  float v = (k < halfK) ? B0[k * GN + c] : B1[(k - halfK) * GN + c];
  Bp[id] = (short)f2bf(v);
}

// C[M x GN] = A[M x K](bf16) * Bp + bias, optional relu.
// 128x128 tile / block, 4 waves 2x2, each wave 64x64 (4x4 16x16x32 frags).
template <int KK, int NBTOT, bool RELU, bool OUT_BF16>
__global__ __launch_bounds__(256) void k_gemm(const short* __restrict__ A, int lda,
                                              const short* __restrict__ Bp,
                                              const float* __restrict__ bias,
                                              void* __restrict__ out, int ldc,
                                              int col_off, int mlimit) {
  const int lane = threadIdx.x & 63;
  const int wave = threadIdx.x >> 6;
  const int wr = wave >> 1, wc = wave & 1;
  const int row0 = blockIdx.x * 128 + wr * 64;
  const int colbase = blockIdx.y * 128 + wc * 64;
  const int arow = lane & 15;
  const int kgrp = lane >> 4;

  f32x4 acc[4][4];
  const f32x4 zero = {0.f, 0.f, 0.f, 0.f};
  #pragma unroll
  for (int a = 0; a < 4; ++a)
    #pragma unroll
    for (int b = 0; b < 4; ++b) acc[a][b] = zero;

  const short* Bbase = Bp + (size_t)lane * 8;
  for (int kk = 0; kk < KK; ++kk) {
    short8 af[4], bfr[4];
    const int kb = kk * 32 + kgrp * 8;
    #pragma unroll
    for (int mi = 0; mi < 4; ++mi)
      af[mi] = *(const short8*)(A + (size_t)(row0 + mi * 16 + arow) * lda + kb);
    #pragma unroll
    for (int ni = 0; ni < 4; ++ni) {
      int nb = (colbase >> 4) + ni;
      bfr[ni] = *(const short8*)(Bbase + ((size_t)(kk * NBTOT + nb) << 9));
    }
    #pragma unroll
    for (int mi = 0; mi < 4; ++mi)
      #pragma unroll
      for (int ni = 0; ni < 4; ++ni)
        acc[mi][ni] = __builtin_amdgcn_mfma_f32_16x16x32_bf16(af[mi], bfr[ni],
                                                              acc[mi][ni], 0, 0, 0);
  }

  const int ccol = lane & 15;
  const int crow = (lane >> 4) * 4;
  #pragma unroll
  for (int ni = 0; ni < 4; ++ni) {
    const int colg = colbase + ni * 16 + ccol;
    const float bv = bias[colg];
    #pragma unroll
    for (int mi = 0; mi < 4; ++mi) {
      #pragma unroll
      for (int j = 0; j < 4; ++j) {
        int rowg = row0 + mi * 16 + crow + j;
        float v = acc[mi][ni][j] + bv;
        if (RELU) v = fmaxf(v, 0.0f);
        if (OUT_BF16) {
          ((short*)out)[(size_t)rowg * ldc + col_off + colg] = (short)f2bf(v);
        } else {
          if (rowg < mlimit)
            ((float*)out)[(size_t)rowg * ldc + col_off + colg] = v;
        }
      }
    }
  }
}

extern "C" void kernel_launch(void* const* d_in, const int* in_sizes, int n_in,
                              void* d_out, int out_size, void* d_ws, size_t ws_size,
                              hipStream_t stream) {
  const float* x   = (const float*)d_in[0];
  const int*   row = (const int*)d_in[1];
  const int*   col = (const int*)d_in[2];
  const float* Wl1 = (const float*)d_in[3];
  const float* bl1 = (const float*)d_in[4];
  const float* Wr1 = (const float*)d_in[5];
  const float* Wl2 = (const float*)d_in[6];
  const float* bl2 = (const float*)d_in[7];
  const float* Wr2 = (const float*)d_in[8];
  float* out = (float*)d_out;

  char* w = (char*)d_ws;
  auto alloc = [&](size_t bytes) {
    char* p = w;
    w += (bytes + 255) & ~(size_t)255;
    return p;
  };
  short* Acat = (short*)alloc((size_t)MPAD * 256 * 2);  // [agg_x_bf16 | x_bf16]
  short* Hcat = (short*)alloc((size_t)MPAD * 512 * 2);  // [agg_h_bf16 | h_bf16]
  short* Bp1  = (short*)alloc(65536 * 2);               // [Wl1;Wr1] packed
  short* Bp2  = (short*)alloc(65536 * 2);               // [Wl2;Wr2] packed
  int* rp   = (int*)alloc((N_NODES + 1) * 4);
  int* cs   = (int*)alloc((size_t)N_EDGES * 4);
  unsigned* tmp = (unsigned*)alloc((size_t)N_EDGES * 4);
  int* Hc   = (int*)alloc((size_t)NB * NBLK_A * 4);
  int* G    = (int*)alloc((size_t)NB * NBLK_A * 4);
  int* Boff = (int*)alloc((NB + 1) * 4);

  // --- CSR build: two-level counting sort (no global data atomics) ---
  k_bhist<<<NBLK_A, 256, 0, stream>>>(row, Hc);
  k_bscan<<<1, 512, 0, stream>>>(Hc, Boff);
  k_bexp<<<NB, 64, 0, stream>>>(Hc, Boff, G);
  k_bscat<<<NBLK_A, 256, 0, stream>>>(row, col, G, tmp);
  k_bsort<<<NB, 256, 0, stream>>>(tmp, Boff, rp, cs);

  // --- weight packing + x conversion (independent of CSR) ---
  k_cvt_x<<<(N_NODES * 32 + 255) / 256, 256, 0, stream>>>(x, Acat);
  k_pack<<<256, 256, 0, stream>>>(Wl1, Wr1, Bp1, 256, 256);
  k_pack<<<256, 256, 0, stream>>>(Wl2, Wr2, Bp2, 512, 128);

  // --- layer 1: agg(x) ; h = relu([agg|x] @ [Wl1;Wr1] + bl1) ---
  k_agg_x<<<(N_NODES + 3) / 4, 256, 0, stream>>>(rp, cs, Acat);
  k_gemm<8, 16, true, true><<<dim3(MTILES, 2), 256, 0, stream>>>(
      Acat, 256, Bp1, bl1, Hcat, 512, 256, MPAD);

  // --- layer 2: agg(h) ; out = [agg|h] @ [Wl2;Wr2] + bl2 ---
  k_agg_h<<<(N_NODES + 3) / 4, 256, 0, stream>>>(rp, cs, Hcat);
  k_gemm<16, 8, false, false><<<dim3(MTILES, 1), 256, 0, stream>>>(
      Hcat, 512, Bp2, bl2, out, 128, 0, N_NODES);
}

// Round 3
// 309.289 us; speedup vs baseline: 1.6196x; 1.1429x over previous
//
#include <hip/hip_runtime.h>

#define N_NODES 100000
#define N_EDGES 1600000
#define MPAD    100096   /* 782 * 128 */
#define MTILES  782

#define NB      391      /* ceil(100000/256) buckets of 256 nodes */
#define CH      8192     /* edges per phase-A block */
#define NBLK_A  196      /* ceil(1600000/8192) */

typedef __attribute__((ext_vector_type(8))) short short8;
typedef __attribute__((ext_vector_type(4))) float f32x4;

static __device__ __forceinline__ unsigned short f2bf(float f) {
  unsigned u = __builtin_bit_cast(unsigned, f);
  u += 0x7fffu + ((u >> 16) & 1u);     // round-to-nearest-even
  return (unsigned short)(u >> 16);
}
static __device__ __forceinline__ float bf2f(unsigned short s) {
  unsigned u = ((unsigned)s) << 16;
  return __builtin_bit_cast(float, u);
}

// ---------------- CSR build: two-level LDS counting sort ----------------

__global__ __launch_bounds__(256) void k_bhist(const int* __restrict__ row,
                                               int* __restrict__ Hc) {
  __shared__ int hist[NB];
  int b = blockIdx.x, t = threadIdx.x;
  for (int j = t; j < NB; j += 256) hist[j] = 0;
  __syncthreads();
  int base = b * CH;
  #pragma unroll
  for (int k = 0; k < 8; ++k) {
    int i = base + k * 1024 + t * 4;
    if (i < N_EDGES) {
      int4 r = *(const int4*)(row + i);
      atomicAdd(&hist[r.x >> 8], 1);
      atomicAdd(&hist[r.y >> 8], 1);
      atomicAdd(&hist[r.z >> 8], 1);
      atomicAdd(&hist[r.w >> 8], 1);
    }
  }
  __syncthreads();
  for (int j = t; j < NB; j += 256) Hc[j * NBLK_A + b] = hist[j];
}

__global__ __launch_bounds__(512) void k_bscan(const int* __restrict__ Hc,
                                               int* __restrict__ Boff) {
  int t = threadIdx.x;
  int total = 0;
  if (t < NB) {
    const int* p = Hc + t * NBLK_A;
    for (int i = 0; i < NBLK_A; i += 4) {
      int4 v = *(const int4*)(p + i);
      total += v.x + v.y + v.z + v.w;
    }
  }
  int lane = t & 63, w = t >> 6;
  int incl = total;
  #pragma unroll
  for (int off = 1; off < 64; off <<= 1) {
    int n = __shfl_up(incl, off, 64);
    if (lane >= off) incl += n;
  }
  __shared__ int ws[8];
  if (lane == 63) ws[w] = incl;
  __syncthreads();
  int wo = 0;
  for (int ww = 0; ww < w; ++ww) wo += ws[ww];
  int excl = wo + incl - total;
  if (t < NB) Boff[t] = excl;
  if (t == NB - 1) Boff[NB] = excl + total;
}

__global__ __launch_bounds__(64) void k_bexp(const int* __restrict__ Hc,
                                             const int* __restrict__ Boff,
                                             int* __restrict__ G) {
  int b = blockIdx.x, l = threadIdx.x;
  int run = Boff[b];
  const int* p = Hc + b * NBLK_A;
  for (int c = 0; c < NBLK_A; c += 64) {
    int idx = c + l;
    int v = (idx < NBLK_A) ? p[idx] : 0;
    int incl = v;
    #pragma unroll
    for (int off = 1; off < 64; off <<= 1) {
      int n = __shfl_up(incl, off, 64);
      if (l >= off) incl += n;
    }
    if (idx < NBLK_A) G[b * NBLK_A + idx] = run + incl - v;
    run += __shfl(incl, 63, 64);
  }
}

__global__ __launch_bounds__(256) void k_bscat(const int* __restrict__ row,
                                               const int* __restrict__ col,
                                               const int* __restrict__ G,
                                               unsigned* __restrict__ tmp) {
  __shared__ int cur[NB];
  int b = blockIdx.x, t = threadIdx.x;
  for (int j = t; j < NB; j += 256) cur[j] = G[j * NBLK_A + b];
  __syncthreads();
  int base = b * CH;
  #pragma unroll
  for (int k = 0; k < 8; ++k) {
    int i = base + k * 1024 + t * 4;
    if (i < N_EDGES) {
      int4 r = *(const int4*)(row + i);
      int4 c = *(const int4*)(col + i);
      int p0 = atomicAdd(&cur[r.x >> 8], 1);
      tmp[p0] = (unsigned)c.x | ((unsigned)(r.x & 255) << 24);
      int p1 = atomicAdd(&cur[r.y >> 8], 1);
      tmp[p1] = (unsigned)c.y | ((unsigned)(r.y & 255) << 24);
      int p2 = atomicAdd(&cur[r.z >> 8], 1);
      tmp[p2] = (unsigned)c.z | ((unsigned)(r.z & 255) << 24);
      int p3 = atomicAdd(&cur[r.w >> 8], 1);
      tmp[p3] = (unsigned)c.w | ((unsigned)(r.w & 255) << 24);
    }
  }
}

__global__ __launch_bounds__(256) void k_bsort(const unsigned* __restrict__ tmp,
                                               const int* __restrict__ Boff,
                                               int* __restrict__ rp,
                                               int* __restrict__ cs) {
  __shared__ int hist[256];
  __shared__ int wsum[4];
  int b = blockIdx.x, t = threadIdx.x;
  int s = Boff[b], e = Boff[b + 1];
  hist[t] = 0;
  __syncthreads();
  for (int i = s + t; i < e; i += 256) atomicAdd(&hist[tmp[i] >> 24], 1);
  __syncthreads();
  int v = hist[t];
  int lane = t & 63, w = t >> 6;
  int incl = v;
  #pragma unroll
  for (int off = 1; off < 64; off <<= 1) {
    int n = __shfl_up(incl, off, 64);
    if (lane >= off) incl += n;
  }
  if (lane == 63) wsum[w] = incl;
  __syncthreads();
  int wo = 0;
  for (int ww = 0; ww < w; ++ww) wo += wsum[ww];
  int excl = s + wo + incl - v;
  int node = (b << 8) + t;
  if (node < N_NODES) rp[node] = excl;
  __syncthreads();
  hist[t] = excl;    // reuse as cursor
  __syncthreads();
  for (int i = s + t; i < e; i += 256) {
    unsigned u = tmp[i];
    int pos = atomicAdd(&hist[u >> 24], 1);
    cs[pos] = (int)(u & 0xFFFFFFu);
  }
  if (b == 0 && t == 0) rp[N_NODES] = N_EDGES;
}

// ---------------- feature conversion / aggregation ----------------

// x f32 -> bf16 into Acat[:,128:256]
__global__ void k_cvt_x(const float* __restrict__ x, short* __restrict__ Acat) {
  int id = blockIdx.x * 256 + threadIdx.x;
  if (id >= N_NODES * 32) return;
  int node = id >> 5, c4 = id & 31;
  float4 v = *(const float4*)(x + (size_t)node * 128 + c4 * 4);
  uint2 u;
  u.x = (unsigned)f2bf(v.x) | ((unsigned)f2bf(v.y) << 16);
  u.y = (unsigned)f2bf(v.z) | ((unsigned)f2bf(v.w) << 16);
  *(uint2*)(Acat + (size_t)node * 256 + 128 + c4 * 4) = u;
}

// agg over bf16 x (read Acat[:,128:256]) -> bf16 into Acat[:,0:128]. 1 wave/node.
__global__ __launch_bounds__(256) void k_agg_x(const int* __restrict__ rp,
                                               const int* __restrict__ cs,
                                               short* __restrict__ Acat) {
  int node = blockIdx.x * 4 + (threadIdx.x >> 6);
  if (node >= N_NODES) return;
  int lane = threadIdx.x & 63;
  int s = rp[node], e = rp[node + 1];
  float a0 = 0.f, a1 = 0.f;
  const short* xb = Acat + 128 + 2 * lane;
  int i = s;
  for (; i + 8 <= e; i += 8) {
    unsigned u[8];
    #pragma unroll
    for (int q = 0; q < 8; ++q)
      u[q] = *(const unsigned*)(xb + (size_t)cs[i + q] * 256);
    #pragma unroll
    for (int q = 0; q < 8; ++q) {
      a0 += bf2f((unsigned short)u[q]);
      a1 += bf2f((unsigned short)(u[q] >> 16));
    }
  }
  for (; i < e; ++i) {
    unsigned u = *(const unsigned*)(xb + (size_t)cs[i] * 256);
    a0 += bf2f((unsigned short)u);
    a1 += bf2f((unsigned short)(u >> 16));
  }
  *(unsigned*)(Acat + (size_t)node * 256 + 2 * lane) =
      (unsigned)f2bf(a0) | ((unsigned)f2bf(a1) << 16);
}

// agg over P[:,0:128] (bf16) + residual P[node,128:256] -> f32 out. 1 wave/node.
__global__ __launch_bounds__(256) void k_agg_p(const int* __restrict__ rp,
                                               const int* __restrict__ cs,
                                               const short* __restrict__ P,
                                               float* __restrict__ out) {
  int node = blockIdx.x * 4 + (threadIdx.x >> 6);
  if (node >= N_NODES) return;
  int lane = threadIdx.x & 63;
  int s = rp[node], e = rp[node + 1];
  float a0 = 0.f, a1 = 0.f;
  const short* pb = P + 2 * lane;
  int i = s;
  for (; i + 8 <= e; i += 8) {
    unsigned u[8];
    #pragma unroll
    for (int q = 0; q < 8; ++q)
      u[q] = *(const unsigned*)(pb + (size_t)cs[i + q] * 256);
    #pragma unroll
    for (int q = 0; q < 8; ++q) {
      a0 += bf2f((unsigned short)u[q]);
      a1 += bf2f((unsigned short)(u[q] >> 16));
    }
  }
  for (; i < e; ++i) {
    unsigned u = *(const unsigned*)(pb + (size_t)cs[i] * 256);
    a0 += bf2f((unsigned short)u);
    a1 += bf2f((unsigned short)(u >> 16));
  }
  unsigned r = *(const unsigned*)(P + (size_t)node * 256 + 128 + 2 * lane);
  a0 += bf2f((unsigned short)r);
  a1 += bf2f((unsigned short)(r >> 16));
  float2 o = {a0, a1};
  *(float2*)(out + (size_t)node * 128 + 2 * lane) = o;
}

// ---------------- GEMM ----------------

// pack B [K x GN] f32 -> bf16 MFMA-B fragment layout.
// HCAT=false: B = vstack(B0,B1)  (B0,B1 are (K/2) x GN)
// HCAT=true:  B = hstack(B0,B1)  (B0,B1 are K x (GN/2))
template <bool HCAT>
__global__ void k_pack(const float* __restrict__ B0, const float* __restrict__ B1,
                       short* __restrict__ Bp, int K, int GN) {
  int id = blockIdx.x * 256 + threadIdx.x;
  if (id >= K * GN) return;
  int j = id & 7;
  int lane = (id >> 3) & 63;
  int blk = id >> 9;
  int NBf = GN >> 4;
  int nb = blk % NBf;
  int kk = blk / NBf;
  int k = kk * 32 + (lane >> 4) * 8 + j;
  int c = nb * 16 + (lane & 15);
  float v;
  if (HCAT) {
    int half = GN >> 1;
    v = (c < half) ? B0[k * half + c] : B1[k * half + (c - half)];
  } else {
    int halfK = K >> 1;
    v = (k < halfK) ? B0[k * GN + c] : B1[(k - halfK) * GN + c];
  }
  Bp[id] = (short)f2bf(v);
}

// C[M x GN] = A[M x K](bf16) * Bp (+bias per BIAS_MODE), optional relu.
// 128x128 tile / block, 4 waves 2x2, each wave 64x64 (4x4 16x16x32 frags).
// BIAS_MODE: 0 = bias[colg]; 1 = colg<128 ? 0 : bias[colg-128]
template <int KK, int NBTOT, bool RELU, bool OUT_BF16, int BIAS_MODE>
__global__ __launch_bounds__(256) void k_gemm(const short* __restrict__ A, int lda,
                                              const short* __restrict__ Bp,
                                              const float* __restrict__ bias,
                                              void* __restrict__ out, int ldc,
                                              int col_off, int mlimit) {
  const int lane = threadIdx.x & 63;
  const int wave = threadIdx.x >> 6;
  const int wr = wave >> 1, wc = wave & 1;
  const int row0 = blockIdx.x * 128 + wr * 64;
  const int colbase = blockIdx.y * 128 + wc * 64;
  const int arow = lane & 15;
  const int kgrp = lane >> 4;

  f32x4 acc[4][4];
  const f32x4 zero = {0.f, 0.f, 0.f, 0.f};
  #pragma unroll
  for (int a = 0; a < 4; ++a)
    #pragma unroll
    for (int b = 0; b < 4; ++b) acc[a][b] = zero;

  const short* Bbase = Bp + (size_t)lane * 8;
  for (int kk = 0; kk < KK; ++kk) {
    short8 af[4], bfr[4];
    const int kb = kk * 32 + kgrp * 8;
    #pragma unroll
    for (int mi = 0; mi < 4; ++mi)
      af[mi] = *(const short8*)(A + (size_t)(row0 + mi * 16 + arow) * lda + kb);
    #pragma unroll
    for (int ni = 0; ni < 4; ++ni) {
      int nb = (colbase >> 4) + ni;
      bfr[ni] = *(const short8*)(Bbase + ((size_t)(kk * NBTOT + nb) << 9));
    }
    #pragma unroll
    for (int mi = 0; mi < 4; ++mi)
      #pragma unroll
      for (int ni = 0; ni < 4; ++ni)
        acc[mi][ni] = __builtin_amdgcn_mfma_f32_16x16x32_bf16(af[mi], bfr[ni],
                                                              acc[mi][ni], 0, 0, 0);
  }

  const int ccol = lane & 15;
  const int crow = (lane >> 4) * 4;
  #pragma unroll
  for (int ni = 0; ni < 4; ++ni) {
    const int colg = colbase + ni * 16 + ccol;
    float bv;
    if (BIAS_MODE == 0) bv = bias[colg];
    else bv = (colg < 128) ? 0.f : bias[colg - 128];
    #pragma unroll
    for (int mi = 0; mi < 4; ++mi) {
      #pragma unroll
      for (int j = 0; j < 4; ++j) {
        int rowg = row0 + mi * 16 + crow + j;
        float v = acc[mi][ni][j] + bv;
        if (RELU) v = fmaxf(v, 0.0f);
        if (OUT_BF16) {
          ((short*)out)[(size_t)rowg * ldc + col_off + colg] = (short)f2bf(v);
        } else {
          if (rowg < mlimit)
            ((float*)out)[(size_t)rowg * ldc + col_off + colg] = v;
        }
      }
    }
  }
}

extern "C" void kernel_launch(void* const* d_in, const int* in_sizes, int n_in,
                              void* d_out, int out_size, void* d_ws, size_t ws_size,
                              hipStream_t stream) {
  const float* x   = (const float*)d_in[0];
  const int*   row = (const int*)d_in[1];
  const int*   col = (const int*)d_in[2];
  const float* Wl1 = (const float*)d_in[3];
  const float* bl1 = (const float*)d_in[4];
  const float* Wr1 = (const float*)d_in[5];
  const float* Wl2 = (const float*)d_in[6];
  const float* bl2 = (const float*)d_in[7];
  const float* Wr2 = (const float*)d_in[8];
  float* out = (float*)d_out;

  char* w = (char*)d_ws;
  auto alloc = [&](size_t bytes) {
    char* p = w;
    w += (bytes + 255) & ~(size_t)255;
    return p;
  };
  short* Acat = (short*)alloc((size_t)MPAD * 256 * 2);  // [agg_x_bf16 | x_bf16]
  short* Hbuf = (short*)alloc((size_t)MPAD * 256 * 2);  // h (post-relu), bf16
  short* P    = (short*)alloc((size_t)MPAD * 256 * 2);  // [h@Wl2 | h@Wr2+bl2], bf16
  short* Bp1  = (short*)alloc(65536 * 2);               // [Wl1;Wr1] packed (vcat)
  short* Bp2  = (short*)alloc(65536 * 2);               // [Wl2|Wr2] packed (hcat)
  int* rp   = (int*)alloc((N_NODES + 1) * 4);
  int* cs   = (int*)alloc((size_t)N_EDGES * 4);
  unsigned* tmp = (unsigned*)alloc((size_t)N_EDGES * 4);
  int* Hc   = (int*)alloc((size_t)NB * NBLK_A * 4);
  int* G    = (int*)alloc((size_t)NB * NBLK_A * 4);
  int* Boff = (int*)alloc((NB + 1) * 4);

  // --- CSR build: two-level counting sort (no global data atomics) ---
  k_bhist<<<NBLK_A, 256, 0, stream>>>(row, Hc);
  k_bscan<<<1, 512, 0, stream>>>(Hc, Boff);
  k_bexp<<<NB, 64, 0, stream>>>(Hc, Boff, G);
  k_bscat<<<NBLK_A, 256, 0, stream>>>(row, col, G, tmp);
  k_bsort<<<NB, 256, 0, stream>>>(tmp, Boff, rp, cs);

  // --- weight packing + x conversion (independent of CSR) ---
  k_cvt_x<<<(N_NODES * 32 + 255) / 256, 256, 0, stream>>>(x, Acat);
  k_pack<false><<<256, 256, 0, stream>>>(Wl1, Wr1, Bp1, 256, 256);
  k_pack<true><<<256, 256, 0, stream>>>(Wl2, Wr2, Bp2, 256, 256);

  // --- layer 1: agg(x) ; h = relu([agg|x] @ [Wl1;Wr1] + bl1) -> Hbuf bf16 ---
  k_agg_x<<<(N_NODES + 3) / 4, 256, 0, stream>>>(rp, cs, Acat);
  k_gemm<8, 16, true, true, 0><<<dim3(MTILES, 2), 256, 0, stream>>>(
      Acat, 256, Bp1, bl1, Hbuf, 256, 0, MPAD);

  // --- layer 2: P = h @ [Wl2 | Wr2] (+bl2 on right half) ; out = agg(P_l) + P_r ---
  k_gemm<8, 16, false, true, 1><<<dim3(MTILES, 2), 256, 0, stream>>>(
      Hbuf, 256, Bp2, bl2, P, 256, 0, MPAD);
  k_agg_p<<<(N_NODES + 3) / 4, 256, 0, stream>>>(rp, cs, P, out);
}